// Round 1
// baseline (806.733 us; speedup 1.0000x reference)
//
#include <hip/hip_runtime.h>
#include <hip/hip_bf16.h>

// ---------------------------------------------------------------------------
// GAE: 2x GCNConv (self-loops, sym-norm) + edge dot decoder.
// Strategy: build CSR (by dst) once per call from scratch (ws is re-poisoned),
// then: h1 = x@W1 (fp32 tiled GEMM) -> CSR-aggregate(+b1,ReLU) -> z1
//       h2 = z1@W2 -> CSR-aggregate(+b2) -> z2 -> edge dot decode.
// All deterministic-shape, no host sync, graph-capture safe.
// ---------------------------------------------------------------------------

#define CHUNK 512  // scan chunk

__global__ void init_k(int* __restrict__ cnt, int* __restrict__ fill, int n) {
  int i = blockIdx.x * blockDim.x + threadIdx.x;
  if (i < n) { cnt[i] = 0; fill[i] = 0; }
}

__global__ void count_k(const int* __restrict__ dst, int* __restrict__ cnt, int E) {
  int i = blockIdx.x * blockDim.x + threadIdx.x;
  if (i < E) atomicAdd(&cnt[dst[i]], 1);
}

__global__ void dis_k(const int* __restrict__ cnt, float* __restrict__ dis, int n) {
  int i = blockIdx.x * blockDim.x + threadIdx.x;
  if (i < n) dis[i] = rsqrtf((float)(cnt[i] + 1));  // +1: self loop
}

// per-chunk exclusive scan; chunk totals to bsum
__global__ void chunk_scan_k(const int* __restrict__ cnt, int* __restrict__ rp,
                             int* __restrict__ bsum, int n) {
  __shared__ int s[CHUNK];
  int t = threadIdx.x, b = blockIdx.x;
  int i = b * CHUNK + t;
  int v = (i < n) ? cnt[i] : 0;
  s[t] = v;
  __syncthreads();
  for (int off = 1; off < CHUNK; off <<= 1) {
    int u = (t >= off) ? s[t - off] : 0;
    __syncthreads();
    s[t] += u;
    __syncthreads();
  }
  if (i < n) rp[i] = s[t] - v;  // local exclusive
  if (t == CHUNK - 1) bsum[b] = s[t];
}

// single block: exclusive-scan chunk sums in place; write rp[n] = total
__global__ void scan_sums_k(int* __restrict__ bsum, int* __restrict__ rp,
                            int nchunks, int n) {
  __shared__ int s[CHUNK];
  int t = threadIdx.x;
  int v = (t < nchunks) ? bsum[t] : 0;
  s[t] = v;
  __syncthreads();
  for (int off = 1; off < CHUNK; off <<= 1) {
    int u = (t >= off) ? s[t - off] : 0;
    __syncthreads();
    s[t] += u;
    __syncthreads();
  }
  if (t < nchunks) bsum[t] = s[t] - v;  // exclusive
  if (t == nchunks - 1) rp[n] = s[t];   // grand total = E
}

__global__ void add_off_k(int* __restrict__ rp, const int* __restrict__ bsum, int n) {
  int i = blockIdx.x * CHUNK + threadIdx.x;
  if (i < n) rp[i] += bsum[blockIdx.x];
}

__global__ void scatter_k(const int* __restrict__ src, const int* __restrict__ dst,
                          const int* __restrict__ rp, int* __restrict__ fill,
                          const float* __restrict__ dis, int* __restrict__ col,
                          float* __restrict__ wgt, int E) {
  int i = blockIdx.x * blockDim.x + threadIdx.x;
  if (i < E) {
    int d = dst[i], s = src[i];
    int pos = rp[d] + atomicAdd(&fill[d], 1);
    col[pos] = s;
    wgt[pos] = dis[s] * dis[d];
  }
}

// ---------------- fp32 tiled GEMM: C[M,N] = A[M,K] @ B[K,N] -----------------
#define BM 64
#define BN 64
#define BK 16
__launch_bounds__(256) __global__
void sgemm_k(const float* __restrict__ A, const float* __restrict__ B,
             float* __restrict__ C, int M, int N, int K) {
  __shared__ float As[BK][BM + 4];
  __shared__ float Bs[BK][BN + 4];
  int t = threadIdx.x;
  int tx = t & 15, ty = t >> 4;          // 16x16 thread grid, 4x4 per thread
  int m0 = blockIdx.y * BM;
  int n0 = blockIdx.x * BN;
  int la_r = (t * 4) / BK, la_c = (t * 4) % BK;   // A tile 64x16
  int lb_r = (t * 4) / BN, lb_c = (t * 4) % BN;   // B tile 16x64
  float acc[4][4] = {};
  for (int k0 = 0; k0 < K; k0 += BK) {
    float4 a4 = make_float4(0.f, 0.f, 0.f, 0.f);
    int ar = m0 + la_r;
    if (ar < M) a4 = *reinterpret_cast<const float4*>(A + (size_t)ar * K + k0 + la_c);
    float4 b4 = *reinterpret_cast<const float4*>(B + (size_t)(k0 + lb_r) * N + n0 + lb_c);
    __syncthreads();
    As[la_c + 0][la_r] = a4.x;
    As[la_c + 1][la_r] = a4.y;
    As[la_c + 2][la_r] = a4.z;
    As[la_c + 3][la_r] = a4.w;
    *reinterpret_cast<float4*>(&Bs[lb_r][lb_c]) = b4;
    __syncthreads();
#pragma unroll
    for (int k = 0; k < BK; k++) {
      float a[4], b[4];
#pragma unroll
      for (int i = 0; i < 4; i++) a[i] = As[k][ty * 4 + i];
#pragma unroll
      for (int j = 0; j < 4; j++) b[j] = Bs[k][tx * 4 + j];
#pragma unroll
      for (int i = 0; i < 4; i++)
#pragma unroll
        for (int j = 0; j < 4; j++) acc[i][j] = fmaf(a[i], b[j], acc[i][j]);
    }
  }
#pragma unroll
  for (int i = 0; i < 4; i++) {
    int r = m0 + ty * 4 + i;
    if (r < M) {
      float4 o = make_float4(acc[i][0], acc[i][1], acc[i][2], acc[i][3]);
      *reinterpret_cast<float4*>(C + (size_t)r * N + n0 + tx * 4) = o;
    }
  }
}

// ------------- CSR aggregation: out[d] = sum_e w_e*h[src_e] + dis^2*h[d] + b -
template <int VEC, bool RELU>
__launch_bounds__(256) __global__
void aggregate_k(const float* __restrict__ h, const int* __restrict__ rp,
                 const int* __restrict__ col, const float* __restrict__ wgt,
                 const float* __restrict__ dis, const float* __restrict__ bias,
                 float* __restrict__ out, int n) {
  const int DIM = VEC * 64;
  int wave = threadIdx.x >> 6, lane = threadIdx.x & 63;
  int node = blockIdx.x * (blockDim.x >> 6) + wave;
  if (node >= n) return;
  int start = rp[node], end = rp[node + 1];
  float di = dis[node];
  float sw = di * di;
  float acc[VEC];
  {
    const float* hp = h + (size_t)node * DIM + lane * VEC;
#pragma unroll
    for (int v = 0; v < VEC; v++) acc[v] = hp[v] * sw;  // self loop
  }
  for (int e = start; e < end; e++) {
    int s = col[e];
    float w = wgt[e];
    const float* hs = h + (size_t)s * DIM + lane * VEC;
    if (VEC == 4) {
      float4 hv = *reinterpret_cast<const float4*>(hs);
      acc[0] = fmaf(hv.x, w, acc[0]);
      acc[1] = fmaf(hv.y, w, acc[1]);
      acc[2] = fmaf(hv.z, w, acc[2]);
      acc[3] = fmaf(hv.w, w, acc[3]);
    } else {
      float2 hv = *reinterpret_cast<const float2*>(hs);
      acc[0] = fmaf(hv.x, w, acc[0]);
      acc[1] = fmaf(hv.y, w, acc[1]);
    }
  }
  float* op = out + (size_t)node * DIM + lane * VEC;
#pragma unroll
  for (int v = 0; v < VEC; v++) {
    float r = acc[v] + bias[lane * VEC + v];
    if (RELU) r = fmaxf(r, 0.f);
    op[v] = r;
  }
}

// --------------- decode: y[e] = dot(z[a], z[b]) over 128 dims ---------------
__launch_bounds__(256) __global__
void decode_k(const float* __restrict__ z, const int* __restrict__ ea,
              const int* __restrict__ eb, float* __restrict__ y, int E) {
  int wave = threadIdx.x >> 6, lane = threadIdx.x & 63;
  int e = blockIdx.x * (blockDim.x >> 6) + wave;
  if (e >= E) return;
  int a = ea[e], b = eb[e];
  const float2* za = reinterpret_cast<const float2*>(z + (size_t)a * 128);
  const float2* zb = reinterpret_cast<const float2*>(z + (size_t)b * 128);
  float2 pa = za[lane], pb = zb[lane];
  float s = pa.x * pb.x + pa.y * pb.y;
#pragma unroll
  for (int off = 32; off; off >>= 1) s += __shfl_down(s, off);
  if (lane == 0) y[e] = s;
}

extern "C" void kernel_launch(void* const* d_in, const int* in_sizes, int n_in,
                              void* d_out, int out_size, void* d_ws, size_t ws_size,
                              hipStream_t stream) {
  const float* x = (const float*)d_in[0];
  const int* ei = (const int*)d_in[1];
  const int* eli = (const int*)d_in[2];
  const float* W1 = (const float*)d_in[3];
  const float* b1 = (const float*)d_in[4];
  const float* W2 = (const float*)d_in[5];
  const float* b2 = (const float*)d_in[6];
  float* y = (float*)d_out;

  const int DIN = 256, DH = 256, DOUT = 128;
  const int n = in_sizes[0] / DIN;          // 50000
  const int E = in_sizes[1] / 2;            // 1.6M
  const int EL = in_sizes[2] / 2;           // 100k
  const int* src = ei;
  const int* dst = ei + E;
  const int* ea = eli;
  const int* eb = eli + EL;

  // workspace carve-up (256B aligned)
  size_t off = 0;
  auto alloc = [&](size_t bytes) {
    void* p = (char*)d_ws + off;
    off += (bytes + 255) & ~(size_t)255;
    return p;
  };
  int nchunks = (n + CHUNK - 1) / CHUNK;
  int* cnt = (int*)alloc((size_t)n * 4);
  int* fill = (int*)alloc((size_t)n * 4);
  int* rp = (int*)alloc((size_t)(n + 1) * 4);
  int* bsum = (int*)alloc((size_t)(nchunks + 1) * 4);
  float* dis = (float*)alloc((size_t)n * 4);
  int* col = (int*)alloc((size_t)E * 4);
  float* wgt = (float*)alloc((size_t)E * 4);
  float* h1 = (float*)alloc((size_t)n * DH * 4);  // reused as h2
  float* z1 = (float*)alloc((size_t)n * DH * 4);  // reused as z2
  (void)ws_size;

  // ---- graph prep ----
  init_k<<<(n + 255) / 256, 256, 0, stream>>>(cnt, fill, n);
  count_k<<<(E + 255) / 256, 256, 0, stream>>>(dst, cnt, E);
  dis_k<<<(n + 255) / 256, 256, 0, stream>>>(cnt, dis, n);
  chunk_scan_k<<<nchunks, CHUNK, 0, stream>>>(cnt, rp, bsum, n);
  scan_sums_k<<<1, CHUNK, 0, stream>>>(bsum, rp, nchunks, n);
  add_off_k<<<nchunks, CHUNK, 0, stream>>>(rp, bsum, n);
  scatter_k<<<(E + 255) / 256, 256, 0, stream>>>(src, dst, rp, fill, dis, col, wgt, E);

  // ---- conv1: h1 = x@W1 ; z1 = agg(h1)+b1, relu ----
  {
    dim3 grid(DH / BN, (n + BM - 1) / BM);
    sgemm_k<<<grid, 256, 0, stream>>>(x, W1, h1, n, DH, DIN);
  }
  aggregate_k<4, true><<<(n + 3) / 4, 256, 0, stream>>>(h1, rp, col, wgt, dis, b1, z1, n);

  // ---- conv2: h2 = z1@W2 (into h1 buf) ; z2 = agg(h2)+b2 (into z1 buf... no, new view) ----
  float* h2 = h1;  // h1 no longer needed
  {
    dim3 grid(DOUT / BN, (n + BM - 1) / BM);
    sgemm_k<<<grid, 256, 0, stream>>>(z1, W2, h2, n, DOUT, DH);
  }
  float* z2 = z1 + (size_t)0;  // will overwrite z1 only after h2 fully computed (stream-ordered)
  aggregate_k<2, false><<<(n + 3) / 4, 256, 0, stream>>>(h2, rp, col, wgt, dis, b2, z2, n);

  // ---- decode ----
  decode_k<<<(EL + 3) / 4, 256, 0, stream>>>(z2, ea, eb, y, EL);
}

// Round 2
// 778.884 us; speedup vs baseline: 1.0358x; 1.0358x over previous
//
#include <hip/hip_runtime.h>
#include <hip/hip_bf16.h>

// ---------------------------------------------------------------------------
// GAE: 2x GCNConv (self-loops, sym-norm) + edge dot decoder.
// R1->R2 changes:
//   * aggregate_k: depth-8 software-pipelined edge gathers (MLP for the
//     latency-bound random row fetch).
//   * sgemm_k: templated 128x128 / 64x128 tiles, float4 (b128) LDS reads,
//     8x8 (4x8) per-thread accumulators.
// ---------------------------------------------------------------------------

#define CHUNK 512  // scan chunk

__global__ void init_k(int* __restrict__ cnt, int* __restrict__ fill, int n) {
  int i = blockIdx.x * blockDim.x + threadIdx.x;
  if (i < n) { cnt[i] = 0; fill[i] = 0; }
}

__global__ void count_k(const int* __restrict__ dst, int* __restrict__ cnt, int E) {
  int i = blockIdx.x * blockDim.x + threadIdx.x;
  if (i < E) atomicAdd(&cnt[dst[i]], 1);
}

__global__ void dis_k(const int* __restrict__ cnt, float* __restrict__ dis, int n) {
  int i = blockIdx.x * blockDim.x + threadIdx.x;
  if (i < n) dis[i] = rsqrtf((float)(cnt[i] + 1));  // +1: self loop
}

// per-chunk exclusive scan; chunk totals to bsum
__global__ void chunk_scan_k(const int* __restrict__ cnt, int* __restrict__ rp,
                             int* __restrict__ bsum, int n) {
  __shared__ int s[CHUNK];
  int t = threadIdx.x, b = blockIdx.x;
  int i = b * CHUNK + t;
  int v = (i < n) ? cnt[i] : 0;
  s[t] = v;
  __syncthreads();
  for (int off = 1; off < CHUNK; off <<= 1) {
    int u = (t >= off) ? s[t - off] : 0;
    __syncthreads();
    s[t] += u;
    __syncthreads();
  }
  if (i < n) rp[i] = s[t] - v;  // local exclusive
  if (t == CHUNK - 1) bsum[b] = s[t];
}

// single block: exclusive-scan chunk sums in place; write rp[n] = total
__global__ void scan_sums_k(int* __restrict__ bsum, int* __restrict__ rp,
                            int nchunks, int n) {
  __shared__ int s[CHUNK];
  int t = threadIdx.x;
  int v = (t < nchunks) ? bsum[t] : 0;
  s[t] = v;
  __syncthreads();
  for (int off = 1; off < CHUNK; off <<= 1) {
    int u = (t >= off) ? s[t - off] : 0;
    __syncthreads();
    s[t] += u;
    __syncthreads();
  }
  if (t < nchunks) bsum[t] = s[t] - v;  // exclusive
  if (t == nchunks - 1) rp[n] = s[t];   // grand total = E
}

__global__ void add_off_k(int* __restrict__ rp, const int* __restrict__ bsum, int n) {
  int i = blockIdx.x * CHUNK + threadIdx.x;
  if (i < n) rp[i] += bsum[blockIdx.x];
}

__global__ void scatter_k(const int* __restrict__ src, const int* __restrict__ dst,
                          const int* __restrict__ rp, int* __restrict__ fill,
                          const float* __restrict__ dis, int* __restrict__ col,
                          float* __restrict__ wgt, int E) {
  int i = blockIdx.x * blockDim.x + threadIdx.x;
  if (i < E) {
    int d = dst[i], s = src[i];
    int pos = rp[d] + atomicAdd(&fill[d], 1);
    col[pos] = s;
    wgt[pos] = dis[s] * dis[d];
  }
}

// ---------------- fp32 tiled GEMM: C[M,N] = A[M,K] @ B[K,N] -----------------
// 256 threads as 16x16; thread tile RM x RN; K-tile 16.
template <int TM, int TN, int RM, int RN>
__launch_bounds__(256) __global__
void sgemm_k(const float* __restrict__ A, const float* __restrict__ B,
             float* __restrict__ C, int M, int N, int K) {
  const int TK = 16;
  __shared__ float As[TK][TM + 4];  // transposed: As[k][m]
  __shared__ float Bs[TK][TN + 4];
  int t = threadIdx.x;
  int tx = t & 15, ty = t >> 4;
  int m0 = blockIdx.y * TM, n0 = blockIdx.x * TN;
  float acc[RM][RN] = {};
  const int AU = TM / 64;  // float4 loads per thread for A tile (TM*16/4/256)
  const int BU = TN / 64;
  for (int k0 = 0; k0 < K; k0 += TK) {
    float4 aldg[AU], bldg[BU];
#pragma unroll
    for (int u = 0; u < AU; u++) {
      int idx = t + u * 256;
      int row = idx >> 2, kq = (idx & 3) * 4;
      int gr = m0 + row;
      aldg[u] = make_float4(0.f, 0.f, 0.f, 0.f);
      if (gr < M) aldg[u] = *reinterpret_cast<const float4*>(A + (size_t)gr * K + k0 + kq);
    }
#pragma unroll
    for (int u = 0; u < BU; u++) {
      int idx = t + u * 256;
      int row = idx / (TN / 4), cq = (idx % (TN / 4)) * 4;
      bldg[u] = *reinterpret_cast<const float4*>(B + (size_t)(k0 + row) * N + n0 + cq);
    }
    __syncthreads();  // previous tile's compute done before overwrite
#pragma unroll
    for (int u = 0; u < AU; u++) {
      int idx = t + u * 256;
      int row = idx >> 2, kq = (idx & 3) * 4;
      As[kq + 0][row] = aldg[u].x;
      As[kq + 1][row] = aldg[u].y;
      As[kq + 2][row] = aldg[u].z;
      As[kq + 3][row] = aldg[u].w;
    }
#pragma unroll
    for (int u = 0; u < BU; u++) {
      int idx = t + u * 256;
      int row = idx / (TN / 4), cq = (idx % (TN / 4)) * 4;
      *reinterpret_cast<float4*>(&Bs[row][cq]) = bldg[u];
    }
    __syncthreads();
#pragma unroll
    for (int k = 0; k < TK; k++) {
      float a[RM], b[RN];
#pragma unroll
      for (int i = 0; i < RM; i += 4)
        *reinterpret_cast<float4*>(&a[i]) = *reinterpret_cast<const float4*>(&As[k][ty * RM + i]);
#pragma unroll
      for (int j = 0; j < RN; j += 4)
        *reinterpret_cast<float4*>(&b[j]) = *reinterpret_cast<const float4*>(&Bs[k][tx * RN + j]);
#pragma unroll
      for (int i = 0; i < RM; i++)
#pragma unroll
        for (int j = 0; j < RN; j++) acc[i][j] = fmaf(a[i], b[j], acc[i][j]);
    }
  }
#pragma unroll
  for (int i = 0; i < RM; i++) {
    int r = m0 + ty * RM + i;
    if (r < M) {
#pragma unroll
      for (int j = 0; j < RN; j += 4) {
        float4 o = make_float4(acc[i][j], acc[i][j + 1], acc[i][j + 2], acc[i][j + 3]);
        *reinterpret_cast<float4*>(C + (size_t)r * N + n0 + tx * RN + j) = o;
      }
    }
  }
}

// ------------- CSR aggregation: out[d] = sum_e w_e*h[src_e] + dis^2*h[d] + b -
// Depth-8 software pipeline: batch 8 edges' col/wgt, issue 8 row gathers,
// then accumulate. Raises outstanding-loads per wave for the latency-bound
// random gather.
template <int VEC, bool RELU>
__launch_bounds__(256) __global__
void aggregate_k(const float* __restrict__ h, const int* __restrict__ rp,
                 const int* __restrict__ col, const float* __restrict__ wgt,
                 const float* __restrict__ dis, const float* __restrict__ bias,
                 float* __restrict__ out, int n) {
  const int DIM = VEC * 64;
  const int PF = 8;
  int wave = threadIdx.x >> 6, lane = threadIdx.x & 63;
  int node = blockIdx.x * (blockDim.x >> 6) + wave;
  if (node >= n) return;
  int start = rp[node], end = rp[node + 1];
  float di = dis[node];
  float sw = di * di;
  float acc[VEC];
  {
    const float* hp = h + (size_t)node * DIM + lane * VEC;
#pragma unroll
    for (int v = 0; v < VEC; v++) acc[v] = hp[v] * sw;  // self loop
  }
  int e = start;
  for (; e + PF <= end; e += PF) {
    int s[PF];
    float w[PF];
#pragma unroll
    for (int j = 0; j < PF; j++) { s[j] = col[e + j]; w[j] = wgt[e + j]; }
    if (VEC == 4) {
      float4 r[PF];
#pragma unroll
      for (int j = 0; j < PF; j++)
        r[j] = *reinterpret_cast<const float4*>(h + (size_t)s[j] * DIM + lane * 4);
#pragma unroll
      for (int j = 0; j < PF; j++) {
        acc[0] = fmaf(r[j].x, w[j], acc[0]);
        acc[1] = fmaf(r[j].y, w[j], acc[1]);
        acc[2] = fmaf(r[j].z, w[j], acc[2]);
        acc[3] = fmaf(r[j].w, w[j], acc[3]);
      }
    } else {
      float2 r[PF];
#pragma unroll
      for (int j = 0; j < PF; j++)
        r[j] = *reinterpret_cast<const float2*>(h + (size_t)s[j] * DIM + lane * 2);
#pragma unroll
      for (int j = 0; j < PF; j++) {
        acc[0] = fmaf(r[j].x, w[j], acc[0]);
        acc[1] = fmaf(r[j].y, w[j], acc[1]);
      }
    }
  }
  for (; e < end; e++) {
    int s = col[e];
    float w = wgt[e];
    const float* hs = h + (size_t)s * DIM + lane * VEC;
#pragma unroll
    for (int v = 0; v < VEC; v++) acc[v] = fmaf(hs[v], w, acc[v]);
  }
  float* op = out + (size_t)node * DIM + lane * VEC;
#pragma unroll
  for (int v = 0; v < VEC; v++) {
    float r = acc[v] + bias[lane * VEC + v];
    if (RELU) r = fmaxf(r, 0.f);
    op[v] = r;
  }
}

// --------------- decode: y[e] = dot(z[a], z[b]) over 128 dims ---------------
__launch_bounds__(256) __global__
void decode_k(const float* __restrict__ z, const int* __restrict__ ea,
              const int* __restrict__ eb, float* __restrict__ y, int E) {
  int wave = threadIdx.x >> 6, lane = threadIdx.x & 63;
  int e = blockIdx.x * (blockDim.x >> 6) + wave;
  if (e >= E) return;
  int a = ea[e], b = eb[e];
  const float2* za = reinterpret_cast<const float2*>(z + (size_t)a * 128);
  const float2* zb = reinterpret_cast<const float2*>(z + (size_t)b * 128);
  float2 pa = za[lane], pb = zb[lane];
  float s = pa.x * pb.x + pa.y * pb.y;
#pragma unroll
  for (int off = 32; off; off >>= 1) s += __shfl_down(s, off);
  if (lane == 0) y[e] = s;
}

extern "C" void kernel_launch(void* const* d_in, const int* in_sizes, int n_in,
                              void* d_out, int out_size, void* d_ws, size_t ws_size,
                              hipStream_t stream) {
  const float* x = (const float*)d_in[0];
  const int* ei = (const int*)d_in[1];
  const int* eli = (const int*)d_in[2];
  const float* W1 = (const float*)d_in[3];
  const float* b1 = (const float*)d_in[4];
  const float* W2 = (const float*)d_in[5];
  const float* b2 = (const float*)d_in[6];
  float* y = (float*)d_out;

  const int DIN = 256, DH = 256, DOUT = 128;
  const int n = in_sizes[0] / DIN;          // 50000
  const int E = in_sizes[1] / 2;            // 1.6M
  const int EL = in_sizes[2] / 2;           // 100k
  const int* src = ei;
  const int* dst = ei + E;
  const int* ea = eli;
  const int* eb = eli + EL;

  // workspace carve-up (256B aligned)
  size_t off = 0;
  auto alloc = [&](size_t bytes) {
    void* p = (char*)d_ws + off;
    off += (bytes + 255) & ~(size_t)255;
    return p;
  };
  int nchunks = (n + CHUNK - 1) / CHUNK;
  int* cnt = (int*)alloc((size_t)n * 4);
  int* fill = (int*)alloc((size_t)n * 4);
  int* rp = (int*)alloc((size_t)(n + 1) * 4);
  int* bsum = (int*)alloc((size_t)(nchunks + 1) * 4);
  float* dis = (float*)alloc((size_t)n * 4);
  int* col = (int*)alloc((size_t)E * 4);
  float* wgt = (float*)alloc((size_t)E * 4);
  float* h1 = (float*)alloc((size_t)n * DH * 4);  // reused as h2
  float* z1 = (float*)alloc((size_t)n * DH * 4);  // reused as z2
  (void)ws_size;

  // ---- graph prep ----
  init_k<<<(n + 255) / 256, 256, 0, stream>>>(cnt, fill, n);
  count_k<<<(E + 255) / 256, 256, 0, stream>>>(dst, cnt, E);
  dis_k<<<(n + 255) / 256, 256, 0, stream>>>(cnt, dis, n);
  chunk_scan_k<<<nchunks, CHUNK, 0, stream>>>(cnt, rp, bsum, n);
  scan_sums_k<<<1, CHUNK, 0, stream>>>(bsum, rp, nchunks, n);
  add_off_k<<<nchunks, CHUNK, 0, stream>>>(rp, bsum, n);
  scatter_k<<<(E + 255) / 256, 256, 0, stream>>>(src, dst, rp, fill, dis, col, wgt, E);

  // ---- conv1: h1 = x@W1 ; z1 = agg(h1)+b1, relu ----
  {
    dim3 grid(DH / 128, (n + 127) / 128);
    sgemm_k<128, 128, 8, 8><<<grid, 256, 0, stream>>>(x, W1, h1, n, DH, DIN);
  }
  aggregate_k<4, true><<<(n + 3) / 4, 256, 0, stream>>>(h1, rp, col, wgt, dis, b1, z1, n);

  // ---- conv2: h2 = z1@W2 ; z2 = agg(h2)+b2 ----
  float* h2 = h1;  // h1 no longer needed
  {
    dim3 grid(DOUT / 128, (n + 63) / 64);
    sgemm_k<64, 128, 4, 8><<<grid, 256, 0, stream>>>(z1, W2, h2, n, DOUT, DH);
  }
  float* z2 = z1;  // stream-ordered: h2 fully computed before overwrite begins
  aggregate_k<2, false><<<(n + 3) / 4, 256, 0, stream>>>(h2, rp, col, wgt, dis, b2, z2, n);

  // ---- decode ----
  decode_k<<<(EL + 3) / 4, 256, 0, stream>>>(z2, ea, eb, y, EL);
}

// Round 3
// 634.127 us; speedup vs baseline: 1.2722x; 1.2283x over previous
//
#include <hip/hip_runtime.h>
#include <hip/hip_bf16.h>

// ---------------------------------------------------------------------------
// GAE: 2x GCNConv (self-loops, sym-norm) + edge dot decoder.
// R2->R3: store h (aggregation input) as bf16 -> halves the traffic on the
// bandwidth-ceiling random row-gather path. fp32 accumulation throughout.
// GEMM epilogue converts+stores bf16 directly.
// ---------------------------------------------------------------------------

#define CHUNK 512  // scan chunk

__device__ __forceinline__ unsigned short f2bf_rne(float f) {
  unsigned int b = __float_as_uint(f);
  b += 0x7FFFu + ((b >> 16) & 1u);
  return (unsigned short)(b >> 16);
}
__device__ __forceinline__ float bf_lo(unsigned int u) {  // low 16 bits -> float
  return __uint_as_float(u << 16);
}
__device__ __forceinline__ float bf_hi(unsigned int u) {  // high 16 bits -> float
  return __uint_as_float(u & 0xFFFF0000u);
}

__global__ void init_k(int* __restrict__ cnt, int* __restrict__ fill, int n) {
  int i = blockIdx.x * blockDim.x + threadIdx.x;
  if (i < n) { cnt[i] = 0; fill[i] = 0; }
}

__global__ void count_k(const int* __restrict__ dst, int* __restrict__ cnt, int E) {
  int i = blockIdx.x * blockDim.x + threadIdx.x;
  if (i < E) atomicAdd(&cnt[dst[i]], 1);
}

__global__ void dis_k(const int* __restrict__ cnt, float* __restrict__ dis, int n) {
  int i = blockIdx.x * blockDim.x + threadIdx.x;
  if (i < n) dis[i] = rsqrtf((float)(cnt[i] + 1));  // +1: self loop
}

// per-chunk exclusive scan; chunk totals to bsum
__global__ void chunk_scan_k(const int* __restrict__ cnt, int* __restrict__ rp,
                             int* __restrict__ bsum, int n) {
  __shared__ int s[CHUNK];
  int t = threadIdx.x, b = blockIdx.x;
  int i = b * CHUNK + t;
  int v = (i < n) ? cnt[i] : 0;
  s[t] = v;
  __syncthreads();
  for (int off = 1; off < CHUNK; off <<= 1) {
    int u = (t >= off) ? s[t - off] : 0;
    __syncthreads();
    s[t] += u;
    __syncthreads();
  }
  if (i < n) rp[i] = s[t] - v;  // local exclusive
  if (t == CHUNK - 1) bsum[b] = s[t];
}

// single block: exclusive-scan chunk sums in place; write rp[n] = total
__global__ void scan_sums_k(int* __restrict__ bsum, int* __restrict__ rp,
                            int nchunks, int n) {
  __shared__ int s[CHUNK];
  int t = threadIdx.x;
  int v = (t < nchunks) ? bsum[t] : 0;
  s[t] = v;
  __syncthreads();
  for (int off = 1; off < CHUNK; off <<= 1) {
    int u = (t >= off) ? s[t - off] : 0;
    __syncthreads();
    s[t] += u;
    __syncthreads();
  }
  if (t < nchunks) bsum[t] = s[t] - v;  // exclusive
  if (t == nchunks - 1) rp[n] = s[t];   // grand total = E
}

__global__ void add_off_k(int* __restrict__ rp, const int* __restrict__ bsum, int n) {
  int i = blockIdx.x * CHUNK + threadIdx.x;
  if (i < n) rp[i] += bsum[blockIdx.x];
}

__global__ void scatter_k(const int* __restrict__ src, const int* __restrict__ dst,
                          const int* __restrict__ rp, int* __restrict__ fill,
                          const float* __restrict__ dis, int* __restrict__ col,
                          float* __restrict__ wgt, int E) {
  int i = blockIdx.x * blockDim.x + threadIdx.x;
  if (i < E) {
    int d = dst[i], s = src[i];
    int pos = rp[d] + atomicAdd(&fill[d], 1);
    col[pos] = s;
    wgt[pos] = dis[s] * dis[d];
  }
}

// ---------------- fp32 tiled GEMM: C[M,N] = A[M,K] @ B[K,N] -----------------
// 256 threads as 16x16; thread tile RM x RN (RN==8); K-tile 16.
// OBF: store C as bf16 (packed uint4 of 8 bf16), else fp32 float4.
template <int TM, int TN, int RM, int RN, bool OBF>
__launch_bounds__(256) __global__
void sgemm_k(const float* __restrict__ A, const float* __restrict__ B,
             void* __restrict__ Cv, int M, int N, int K) {
  const int TK = 16;
  __shared__ float As[TK][TM + 4];  // transposed: As[k][m]
  __shared__ float Bs[TK][TN + 4];
  int t = threadIdx.x;
  int tx = t & 15, ty = t >> 4;
  int m0 = blockIdx.y * TM, n0 = blockIdx.x * TN;
  float acc[RM][RN] = {};
  const int AU = TM / 64;
  const int BU = TN / 64;
  for (int k0 = 0; k0 < K; k0 += TK) {
    float4 aldg[AU], bldg[BU];
#pragma unroll
    for (int u = 0; u < AU; u++) {
      int idx = t + u * 256;
      int row = idx >> 2, kq = (idx & 3) * 4;
      int gr = m0 + row;
      aldg[u] = make_float4(0.f, 0.f, 0.f, 0.f);
      if (gr < M) aldg[u] = *reinterpret_cast<const float4*>(A + (size_t)gr * K + k0 + kq);
    }
#pragma unroll
    for (int u = 0; u < BU; u++) {
      int idx = t + u * 256;
      int row = idx / (TN / 4), cq = (idx % (TN / 4)) * 4;
      bldg[u] = *reinterpret_cast<const float4*>(B + (size_t)(k0 + row) * N + n0 + cq);
    }
    __syncthreads();
#pragma unroll
    for (int u = 0; u < AU; u++) {
      int idx = t + u * 256;
      int row = idx >> 2, kq = (idx & 3) * 4;
      As[kq + 0][row] = aldg[u].x;
      As[kq + 1][row] = aldg[u].y;
      As[kq + 2][row] = aldg[u].z;
      As[kq + 3][row] = aldg[u].w;
    }
#pragma unroll
    for (int u = 0; u < BU; u++) {
      int idx = t + u * 256;
      int row = idx / (TN / 4), cq = (idx % (TN / 4)) * 4;
      *reinterpret_cast<float4*>(&Bs[row][cq]) = bldg[u];
    }
    __syncthreads();
#pragma unroll
    for (int k = 0; k < TK; k++) {
      float a[RM], b[RN];
#pragma unroll
      for (int i = 0; i < RM; i += 4)
        *reinterpret_cast<float4*>(&a[i]) = *reinterpret_cast<const float4*>(&As[k][ty * RM + i]);
#pragma unroll
      for (int j = 0; j < RN; j += 4)
        *reinterpret_cast<float4*>(&b[j]) = *reinterpret_cast<const float4*>(&Bs[k][tx * RN + j]);
#pragma unroll
      for (int i = 0; i < RM; i++)
#pragma unroll
        for (int j = 0; j < RN; j++) acc[i][j] = fmaf(a[i], b[j], acc[i][j]);
    }
  }
#pragma unroll
  for (int i = 0; i < RM; i++) {
    int r = m0 + ty * RM + i;
    if (r >= M) continue;
    if (OBF) {
      unsigned short u[RN];
#pragma unroll
      for (int j = 0; j < RN; j++) u[j] = f2bf_rne(acc[i][j]);
      unsigned short* C = (unsigned short*)Cv;
      *reinterpret_cast<uint4*>(C + (size_t)r * N + n0 + tx * RN) =
          *reinterpret_cast<const uint4*>(u);
    } else {
      float* C = (float*)Cv;
#pragma unroll
      for (int j = 0; j < RN; j += 4) {
        float4 o = make_float4(acc[i][j], acc[i][j + 1], acc[i][j + 2], acc[i][j + 3]);
        *reinterpret_cast<float4*>(C + (size_t)r * N + n0 + tx * RN + j) = o;
      }
    }
  }
}

// ------------- CSR aggregation over bf16 h: fp32 accumulate ----------------
// out[d] = sum_e w_e*h[src_e] + dis^2*h[d] + b  (fp32 out)
// VEC = dims per lane (4 -> DIM 256, 8B/lane loads; 2 -> DIM 128, 4B/lane).
template <int VEC, bool RELU>
__launch_bounds__(256) __global__
void aggregate_k(const unsigned short* __restrict__ h, const int* __restrict__ rp,
                 const int* __restrict__ col, const float* __restrict__ wgt,
                 const float* __restrict__ dis, const float* __restrict__ bias,
                 float* __restrict__ out, int n) {
  const int DIM = VEC * 64;
  const int PF = 8;
  int wave = threadIdx.x >> 6, lane = threadIdx.x & 63;
  int node = blockIdx.x * (blockDim.x >> 6) + wave;
  if (node >= n) return;
  int start = rp[node], end = rp[node + 1];
  float di = dis[node];
  float sw = di * di;
  float acc[VEC];
  {  // self loop
    const unsigned short* hp = h + (size_t)node * DIM + lane * VEC;
    if (VEC == 4) {
      uint2 r = *reinterpret_cast<const uint2*>(hp);
      acc[0] = bf_lo(r.x) * sw; acc[1] = bf_hi(r.x) * sw;
      acc[2] = bf_lo(r.y) * sw; acc[3] = bf_hi(r.y) * sw;
    } else {
      unsigned int r = *reinterpret_cast<const unsigned int*>(hp);
      acc[0] = bf_lo(r) * sw; acc[1] = bf_hi(r) * sw;
    }
  }
  int e = start;
  for (; e + PF <= end; e += PF) {
    int s[PF];
    float w[PF];
#pragma unroll
    for (int j = 0; j < PF; j++) { s[j] = col[e + j]; w[j] = wgt[e + j]; }
    if (VEC == 4) {
      uint2 r[PF];
#pragma unroll
      for (int j = 0; j < PF; j++)
        r[j] = *reinterpret_cast<const uint2*>(h + (size_t)s[j] * DIM + lane * 4);
#pragma unroll
      for (int j = 0; j < PF; j++) {
        acc[0] = fmaf(bf_lo(r[j].x), w[j], acc[0]);
        acc[1] = fmaf(bf_hi(r[j].x), w[j], acc[1]);
        acc[2] = fmaf(bf_lo(r[j].y), w[j], acc[2]);
        acc[3] = fmaf(bf_hi(r[j].y), w[j], acc[3]);
      }
    } else {
      unsigned int r[PF];
#pragma unroll
      for (int j = 0; j < PF; j++)
        r[j] = *reinterpret_cast<const unsigned int*>(h + (size_t)s[j] * DIM + lane * 2);
#pragma unroll
      for (int j = 0; j < PF; j++) {
        acc[0] = fmaf(bf_lo(r[j]), w[j], acc[0]);
        acc[1] = fmaf(bf_hi(r[j]), w[j], acc[1]);
      }
    }
  }
  for (; e < end; e++) {
    int s = col[e];
    float w = wgt[e];
    const unsigned short* hs = h + (size_t)s * DIM + lane * VEC;
    if (VEC == 4) {
      uint2 r = *reinterpret_cast<const uint2*>(hs);
      acc[0] = fmaf(bf_lo(r.x), w, acc[0]);
      acc[1] = fmaf(bf_hi(r.x), w, acc[1]);
      acc[2] = fmaf(bf_lo(r.y), w, acc[2]);
      acc[3] = fmaf(bf_hi(r.y), w, acc[3]);
    } else {
      unsigned int r = *reinterpret_cast<const unsigned int*>(hs);
      acc[0] = fmaf(bf_lo(r), w, acc[0]);
      acc[1] = fmaf(bf_hi(r), w, acc[1]);
    }
  }
  float* op = out + (size_t)node * DIM + lane * VEC;
#pragma unroll
  for (int v = 0; v < VEC; v++) {
    float r = acc[v] + bias[lane * VEC + v];
    if (RELU) r = fmaxf(r, 0.f);
    op[v] = r;
  }
}

// --------------- decode: y[e] = dot(z[a], z[b]) over 128 dims ---------------
__launch_bounds__(256) __global__
void decode_k(const float* __restrict__ z, const int* __restrict__ ea,
              const int* __restrict__ eb, float* __restrict__ y, int E) {
  int wave = threadIdx.x >> 6, lane = threadIdx.x & 63;
  int e = blockIdx.x * (blockDim.x >> 6) + wave;
  if (e >= E) return;
  int a = ea[e], b = eb[e];
  const float2* za = reinterpret_cast<const float2*>(z + (size_t)a * 128);
  const float2* zb = reinterpret_cast<const float2*>(z + (size_t)b * 128);
  float2 pa = za[lane], pb = zb[lane];
  float s = pa.x * pb.x + pa.y * pb.y;
#pragma unroll
  for (int off = 32; off; off >>= 1) s += __shfl_down(s, off);
  if (lane == 0) y[e] = s;
}

extern "C" void kernel_launch(void* const* d_in, const int* in_sizes, int n_in,
                              void* d_out, int out_size, void* d_ws, size_t ws_size,
                              hipStream_t stream) {
  const float* x = (const float*)d_in[0];
  const int* ei = (const int*)d_in[1];
  const int* eli = (const int*)d_in[2];
  const float* W1 = (const float*)d_in[3];
  const float* b1 = (const float*)d_in[4];
  const float* W2 = (const float*)d_in[5];
  const float* b2 = (const float*)d_in[6];
  float* y = (float*)d_out;

  const int DIN = 256, DH = 256, DOUT = 128;
  const int n = in_sizes[0] / DIN;          // 50000
  const int E = in_sizes[1] / 2;            // 1.6M
  const int EL = in_sizes[2] / 2;           // 100k
  const int* src = ei;
  const int* dst = ei + E;
  const int* ea = eli;
  const int* eb = eli + EL;

  // workspace carve-up (256B aligned)
  size_t off = 0;
  auto alloc = [&](size_t bytes) {
    void* p = (char*)d_ws + off;
    off += (bytes + 255) & ~(size_t)255;
    return p;
  };
  int nchunks = (n + CHUNK - 1) / CHUNK;
  int* cnt = (int*)alloc((size_t)n * 4);
  int* fill = (int*)alloc((size_t)n * 4);
  int* rp = (int*)alloc((size_t)(n + 1) * 4);
  int* bsum = (int*)alloc((size_t)(nchunks + 1) * 4);
  float* dis = (float*)alloc((size_t)n * 4);
  int* col = (int*)alloc((size_t)E * 4);
  float* wgt = (float*)alloc((size_t)E * 4);
  unsigned short* h1 = (unsigned short*)alloc((size_t)n * DH * 2);  // bf16; reused as h2
  float* z1 = (float*)alloc((size_t)n * DH * 4);                    // fp32; reused as z2
  (void)ws_size;

  // ---- graph prep ----
  init_k<<<(n + 255) / 256, 256, 0, stream>>>(cnt, fill, n);
  count_k<<<(E + 255) / 256, 256, 0, stream>>>(dst, cnt, E);
  dis_k<<<(n + 255) / 256, 256, 0, stream>>>(cnt, dis, n);
  chunk_scan_k<<<nchunks, CHUNK, 0, stream>>>(cnt, rp, bsum, n);
  scan_sums_k<<<1, CHUNK, 0, stream>>>(bsum, rp, nchunks, n);
  add_off_k<<<nchunks, CHUNK, 0, stream>>>(rp, bsum, n);
  scatter_k<<<(E + 255) / 256, 256, 0, stream>>>(src, dst, rp, fill, dis, col, wgt, E);

  // ---- conv1: h1 = bf16(x@W1) ; z1 = agg(h1)+b1, relu (fp32) ----
  {
    dim3 grid(DH / 128, (n + 127) / 128);
    sgemm_k<128, 128, 8, 8, true><<<grid, 256, 0, stream>>>(x, W1, h1, n, DH, DIN);
  }
  aggregate_k<4, true><<<(n + 3) / 4, 256, 0, stream>>>(h1, rp, col, wgt, dis, b1, z1, n);

  // ---- conv2: h2 = bf16(z1@W2) ; z2 = agg(h2)+b2 (fp32) ----
  unsigned short* h2 = h1;  // h1 no longer needed
  {
    dim3 grid(DOUT / 128, (n + 63) / 64);
    sgemm_k<64, 128, 4, 8, true><<<grid, 256, 0, stream>>>(z1, W2, h2, n, DOUT, DH);
  }
  float* z2 = z1;  // stream-ordered: gemm2 consumed z1 before agg2 overwrites
  aggregate_k<2, false><<<(n + 3) / 4, 256, 0, stream>>>(h2, rp, col, wgt, dis, b2, z2, n);

  // ---- decode ----
  decode_k<<<(EL + 3) / 4, 256, 0, stream>>>(z2, ea, eb, y, EL);
}